// Round 10
// baseline (2273.614 us; speedup 1.0000x reference)
//
#include <hip/hip_runtime.h>
#include <math.h>

typedef __attribute__((ext_vector_type(8))) short bf16x8;
typedef __attribute__((ext_vector_type(4))) float f32x4;

#define BB 64
#define TT 2048
#define RR 256
#define BLK 24
#define NTHR 512
#define HB_PAD 776   // 768 + 8: rows 16B-aligned
#define HW_PAD 288   // var stride 144 dw = 16 mod 32: conflict-free row-packed reads

#define MFMA(a, b, c) __builtin_amdgcn_mfma_f32_16x16x32_bf16((a), (b), (c), 0, 0, 0)

__device__ __forceinline__ unsigned short f2bf(float f) {
    unsigned u = __float_as_uint(f);
    return (unsigned short)((u + 0x7FFFu + ((u >> 16) & 1u)) >> 16);  // RNE
}
__device__ __forceinline__ float bf2f(unsigned short h) {
    return __uint_as_float(((unsigned)h) << 16);
}
// HW packed f32->bf16 (RNE on gfx950): D = {bf16(b)<<16 | bf16(a)}
__device__ __forceinline__ unsigned cvt_pk_bf16(float a, float b) {
    unsigned r;
    asm("v_cvt_pk_bf16_f32 %0, %1, %2" : "=v"(r) : "v"(a), "v"(b));
    return r;
}
// Branch-free tanh: 1 - 2/(1+e^{2x}).
__device__ __forceinline__ float fast_tanh(float x) {
    float e = __expf(2.0f * x);
    return 1.0f - 2.0f * __builtin_amdgcn_rcpf(1.0f + e);
}

// ---- Pre-pass: pack tw[tap]*W_fb[tap] into MFMA B-fragment order (bf16) ----
__global__ void pack_weights(const float* __restrict__ W_fb,
                             const float* __restrict__ tapw,
                             unsigned short* __restrict__ bp) {
    int gid = blockIdx.x * 256 + threadIdx.x;
    int l = gid & 63, c = gid >> 6;
    int tap = c >> 7;
    int rem = c & 127;
    int kt = rem >> 4, nt = rem & 15;

    float v0 = tapw[0], v1 = tapw[1], v2 = tapw[2], v3 = tapw[3], v4 = tapw[4];
    float mx = fmaxf(fmaxf(fmaxf(v0, v1), fmaxf(v2, v3)), v4);
    float e0 = expf(v0 - mx), e1 = expf(v1 - mx), e2 = expf(v2 - mx),
          e3 = expf(v3 - mx), e4 = expf(v4 - mx);
    float inv = 1.0f / (e0 + e1 + e2 + e3 + e4);
    float tws[5] = {e0 * inv, e1 * inv, e2 * inv, e3 * inv, e4 * inv};
    float tw = tws[tap];

    int kbase = 32 * kt + 8 * (l >> 4);
    int n = 16 * nt + (l & 15);
    const float* W = W_fb + tap * 65536;
    unsigned short t[8];
#pragma unroll
    for (int j = 0; j < 8; ++j) t[j] = f2bf(tw * W[(kbase + j) * 256 + n]);
    uint4 o;
    o.x = (unsigned)t[0] | ((unsigned)t[1] << 16);
    o.y = (unsigned)t[2] | ((unsigned)t[3] << 16);
    o.z = (unsigned)t[4] | ((unsigned)t[5] << 16);
    o.w = (unsigned)t[6] | ((unsigned)t[7] << 16);
    *(uint4*)(bp + (size_t)(c * 64 + l) * 8) = o;
}

// ---- Main kernel: one WG per batch, 8 waves; wave w owns s in [32w, 32w+32) ----
// R10 changes vs 1877us R6 (R9's far-pipeline reverted: per-step branches +
// critical-path work lost 6%):
//  (1) 4-way MFMA chain split (tap1 c10/c11 and tap4 c40/c41 each split over
//      kt 0-3 / 4-7): dependent chain depth 8->4, shortens the per-step serial
//      path. Commutative reassociation only.
//  (2) Staging rewritten float2-per-lane: b32 LDS writes at 1-dw lane stride
//      (2-way, free) replacing uint2 at 4-dw stride (8-way conflict — this was
//      the bulk of the 12.6M SQ_LDS_BANK_CONFLICT).
//  (3) v_cvt_pk_bf16_f32 (HW RNE) for all hi/lo bf16 packing: update-path VALU
//      16 -> ~8 instr; staging VALU ~4x down.
//  (4) Gl2 read hoisted ahead of the MFMA chain in each step.
__global__ __launch_bounds__(NTHR, 1)
void reservoir_mfma(const float* __restrict__ x,
                    const float* __restrict__ W_in,
                    const float* __restrict__ bias,
                    const unsigned short* __restrict__ bp,
                    float* __restrict__ out)
{
    const int b    = blockIdx.x;
    const int tid  = threadIdx.x;
    const int lane = tid & 63;
    const int w    = tid >> 6;
    const int l15  = lane & 15;
    const int quad = lane >> 4;

    __shared__ float xs[TT];                             // 8 KB
    __shared__ unsigned short hwinb[8][2][HW_PAD];       // 9 KB: h ring, bf16 hi/lo
    __shared__ unsigned short hbcb[BLK][2][HB_PAD];      // 72.8 KB: far history hi/lo
    __shared__ float2 Gl2[BLK][130];                     // 25 KB: far + drive + bias
    __shared__ float hob[BLK][RR];                       // 24 KB: block h output buffer

    for (int i = tid; i < TT; i += NTHR) xs[i] = x[b * TT + i];
    {
        unsigned* hz = (unsigned*)&hwinb[0][0][0];
        for (int i = tid; i < 8 * 2 * HW_PAD / 2; i += NTHR) hz[i] = 0u;
    }

    // Resident B-fragments: tap d=1 (b1) and d=4 (b4).
    const bf16x8* bpv = (const bf16x8*)bp;
    bf16x8 b1[8][2], b4[8][2];
#pragma unroll
    for (int kt = 0; kt < 8; ++kt)
#pragma unroll
        for (int u = 0; u < 2; ++u) {
            int nt = 2 * w + u;
            b1[kt][u] = bpv[((0 * 8 + kt) * 16 + nt) * 64 + lane];
            b4[kt][u] = bpv[((1 * 8 + kt) * 16 + nt) * 64 + lane];
        }

    const int s0g = 32 * w + l15, s1g = s0g + 16;
    const float win0 = W_in[s0g], win1 = W_in[s1g];
    const float bi0 = bias[s0g], bi1 = bias[s1g];
    float hp0 = 0.0f, hp1 = 0.0f;

    const float* outr = out + (size_t)b * TT * RR;
    float*       outw = out + (size_t)b * TT * RR;

    // Row-packed A-operand base pointers:
    const unsigned short* hw1v = &hwinb[0][l15 & 1][0];         // tap1: row parity
    const unsigned short* hw4v = &hwinb[0][(l15 >> 2) & 1][0];  // tap4: rows 0-3/4-7
    const unsigned short* fa1  = &hbcb[16 + (l15 & 7)][(l15 >> 3) & 1][0];  // far t1
    const size_t HWSLOT = 2 * HW_PAD;

    // Packed-write lane mapping: quad -> {hi,lo} x {s0,s1}
    const int varw  = quad >> 1;
    const int s_w   = 32 * w + l15 + ((quad & 1) << 4);
    unsigned short* const hwb = &hwinb[0][0][0];
    const unsigned hw_off = (unsigned)(varw * HW_PAD + s_w);

    __syncthreads();

    for (int t0 = 0; t0 < TT; t0 += BLK) {
        // ---- stage far history (taps 24/96/168) into hbcb, bf16 hi/lo ----
        // float2 per lane: LDS writes land at 1-dw lane stride -> conflict-free.
        // tap-24 rows come from previous block's hob (still resident in LDS).
#pragma unroll
        for (int it = 0; it < 18; ++it) {                 // 18*512 = 9216 = 24*768/2
            int i = it * NTHR + tid;
            int j = i / 384;
            int p = i - j * 384;
            int r = 2 * p;                                 // [0,768) step 2
            int kf = r >> 8, rr = r & 255;
            float2 v = {0.f, 0.f};
            if (kf == 0) {
                if (t0 > 0) v = *(const float2*)&hob[j][rr];
            } else {
                int dk = (kf == 1) ? 96 : 168;
                int tt = t0 + j - dk;
                if (tt >= 0) v = *(const float2*)(outr + (size_t)tt * RR + rr);
            }
            unsigned H = cvt_pk_bf16(v.x, v.y);
            float r0 = v.x - __uint_as_float(H << 16);
            float r1 = v.y - __uint_as_float(H & 0xffff0000u);
            unsigned Q = cvt_pk_bf16(r0, r1);
            *(unsigned*)&hbcb[j][0][r] = H;
            *(unsigned*)&hbcb[j][1][r] = Q;
        }
        __syncthreads();

        // ---- far GEMM: C[24 j][32 s/wave] over K=768; tile0 hi+lo chains,
        //      tile1 row-packed; B prefetch depth 3 (rotation) ----
        f32x4 zf = {0.f, 0.f, 0.f, 0.f};
        f32x4 cf00a = zf, cf01a = zf, cf00b = zf, cf01b = zf, cf10 = zf, cf11 = zf;
        const int r0a = l15;              // m-tile 0: j = 0..15
        const int cw0 = 2 * w, cw1 = 2 * w + 1;
        bf16x8 p0A = bpv[((16 + 0) * 16 + cw0) * 64 + lane];
        bf16x8 p0B = bpv[((16 + 0) * 16 + cw1) * 64 + lane];
        bf16x8 p1A = bpv[((16 + 1) * 16 + cw0) * 64 + lane];
        bf16x8 p1B = bpv[((16 + 1) * 16 + cw1) * 64 + lane];
        bf16x8 p2A = bpv[((16 + 2) * 16 + cw0) * 64 + lane];
        bf16x8 p2B = bpv[((16 + 2) * 16 + cw1) * 64 + lane];
#pragma unroll 1
        for (int g = 0; g < 8; ++g) {
            const int base = 3 * g;
            {
                int ro = 32 * base + 8 * quad;
                bf16x8 a00 = *(const bf16x8*)&hbcb[r0a][0][ro];
                bf16x8 a01 = *(const bf16x8*)&hbcb[r0a][1][ro];
                bf16x8 a1  = *(const bf16x8*)&fa1[ro];
                cf00a = MFMA(a00, p0A, cf00a); cf01a = MFMA(a00, p0B, cf01a);
                cf00b = MFMA(a01, p0A, cf00b); cf01b = MFMA(a01, p0B, cf01b);
                cf10  = MFMA(a1,  p0A, cf10);  cf11  = MFMA(a1,  p0B, cf11);
                int nf = base + 3; if (nf > 23) nf = 23;
                p0A = bpv[((16 + nf) * 16 + cw0) * 64 + lane];
                p0B = bpv[((16 + nf) * 16 + cw1) * 64 + lane];
            }
            {
                int ro = 32 * (base + 1) + 8 * quad;
                bf16x8 a00 = *(const bf16x8*)&hbcb[r0a][0][ro];
                bf16x8 a01 = *(const bf16x8*)&hbcb[r0a][1][ro];
                bf16x8 a1  = *(const bf16x8*)&fa1[ro];
                cf00a = MFMA(a00, p1A, cf00a); cf01a = MFMA(a00, p1B, cf01a);
                cf00b = MFMA(a01, p1A, cf00b); cf01b = MFMA(a01, p1B, cf01b);
                cf10  = MFMA(a1,  p1A, cf10);  cf11  = MFMA(a1,  p1B, cf11);
                int nf = base + 4; if (nf > 23) nf = 23;
                p1A = bpv[((16 + nf) * 16 + cw0) * 64 + lane];
                p1B = bpv[((16 + nf) * 16 + cw1) * 64 + lane];
            }
            {
                int ro = 32 * (base + 2) + 8 * quad;
                bf16x8 a00 = *(const bf16x8*)&hbcb[r0a][0][ro];
                bf16x8 a01 = *(const bf16x8*)&hbcb[r0a][1][ro];
                bf16x8 a1  = *(const bf16x8*)&fa1[ro];
                cf00a = MFMA(a00, p2A, cf00a); cf01a = MFMA(a00, p2B, cf01a);
                cf00b = MFMA(a01, p2A, cf00b); cf01b = MFMA(a01, p2B, cf01b);
                cf10  = MFMA(a1,  p2A, cf10);  cf11  = MFMA(a1,  p2B, cf11);
                int nf = base + 5; if (nf > 23) nf = 23;
                p2A = bpv[((16 + nf) * 16 + cw0) * 64 + lane];
                p2B = bpv[((16 + nf) * 16 + cw1) * 64 + lane];
            }
        }
        f32x4 cf00 = cf00a + cf00b, cf01 = cf01a + cf01b;
        // tile1 full = hi (quads 0,1) + lo (quads 2,3): combine across lane^32
        float cf10f[4], cf11f[4];
#pragma unroll
        for (int i = 0; i < 4; ++i) {
            cf10f[i] = cf10[i] + __shfl_xor(cf10[i], 32, 64);
            cf11f[i] = cf11[i] + __shfl_xor(cf11[i], 32, 64);
        }
        // writeback + fold bias and drive
#pragma unroll
        for (int i = 0; i < 4; ++i) {
            int j0 = 4 * quad + i;
            int tx0 = t0 + j0; float xv0 = xs[tx0 < TT ? tx0 : TT - 1];
            Gl2[j0][16 * w + l15] =
                make_float2(cf00[i] + bi0 + xv0 * win0, cf01[i] + bi1 + xv0 * win1);
            int j1 = 16 + 4 * quad + i;
            if (j1 < BLK) {
                int tx1 = t0 + j1; float xv1 = xs[tx1 < TT ? tx1 : TT - 1];
                Gl2[j1][16 * w + l15] =
                    make_float2(cf10f[i] + bi0 + xv1 * win0, cf11f[i] + bi1 + xv1 * win1);
            }
        }
        __syncthreads();

        // ---- sequential sub-blocks of 4 steps ----
        const int tend = (t0 + BLK < TT) ? (t0 + BLK) : TT;
#pragma unroll 1
        for (int t4 = t0; t4 < tend; t4 += 4) {
            // tap d=4, row-packed, 4 chains (kt 0-3 / 4-7 per column tile)
            f32x4 c40a = zf, c40b = zf, c41a = zf, c41b = zf;
            const int sl = (t4 - 4 + (l15 & 3)) & 7;
            const unsigned short* hw4 = hw4v + (size_t)sl * HWSLOT;
#pragma unroll
            for (int kt = 0; kt < 4; ++kt) {
                int ro = 32 * kt + 8 * quad;
                bf16x8 a = *(const bf16x8*)&hw4[ro];
                c40a = MFMA(a, b4[kt][0], c40a);
                c41a = MFMA(a, b4[kt][1], c41a);
            }
#pragma unroll
            for (int kt = 4; kt < 8; ++kt) {
                int ro = 32 * kt + 8 * quad;
                bf16x8 a = *(const bf16x8*)&hw4[ro];
                c40b = MFMA(a, b4[kt][0], c40b);
                c41b = MFMA(a, b4[kt][1], c41b);
            }
            f32x4 c40 = c40a + c40b, c41 = c41a + c41b;
            // combine hi+lo across lane^16 (valid on all lanes)
            float c40f[4], c41f[4];
#pragma unroll
            for (int u2 = 0; u2 < 4; ++u2) {
                c40f[u2] = c40[u2] + __shfl_xor(c40[u2], 16, 64);
                c41f[u2] = c41[u2] + __shfl_xor(c41[u2], 16, 64);
            }
            // 4 sequential steps; tap d=1 per step, row-packed hi/lo, 4 chains
#pragma unroll
            for (int u = 0; u < 4; ++u) {
                const int t = t4 + u;
                const int jj = t - t0;
                const int sp = (t - 1) & 7;
                const unsigned short* hw1 = hw1v + (size_t)sp * HWSLOT;
                float2 gl = Gl2[jj][16 * w + l15];   // hoisted: independent of MFMA
                f32x4 c10a = zf, c10b = zf, c11a = zf, c11b = zf;
#pragma unroll
                for (int kt = 0; kt < 4; ++kt) {
                    int ro = 32 * kt + 8 * quad;
                    bf16x8 a = *(const bf16x8*)&hw1[ro];
                    c10a = MFMA(a, b1[kt][0], c10a);
                    c11a = MFMA(a, b1[kt][1], c11a);
                }
#pragma unroll
                for (int kt = 4; kt < 8; ++kt) {
                    int ro = 32 * kt + 8 * quad;
                    bf16x8 a = *(const bf16x8*)&hw1[ro];
                    c10b = MFMA(a, b1[kt][0], c10b);
                    c11b = MFMA(a, b1[kt][1], c11b);
                }
                // update: C rows 4q (hi) and 4q+1 (lo) valid on EVERY quad ->
                // all 64 lanes compute identical h0,h1.
                float f0 = ((c10a[0] + c10a[1]) + (c10b[0] + c10b[1])) + c40f[u] + gl.x;
                float f1 = ((c11a[0] + c11a[1]) + (c11b[0] + c11b[1])) + c41f[u] + gl.y;
                float h0 = 0.9f * hp0 + 0.1f * fast_tanh(f0);
                float h1 = 0.9f * hp1 + 0.1f * fast_tanh(f1);
                hp0 = h0; hp1 = h1;
                // packed bf16 hi/lo via HW cvt_pk (RNE)
                unsigned hh = cvt_pk_bf16(h0, h1);           // lo16=bf(h0), hi16=bf(h1)
                float r0 = h0 - __uint_as_float(hh << 16);
                float r1 = h1 - __uint_as_float(hh & 0xffff0000u);
                unsigned lp = cvt_pk_bf16(r0, r1);
                unsigned sel = varw ? lp : hh;
                unsigned wv = (quad & 1) ? (sel >> 16) : (sel & 0xffffu);
                const int wsl = t & 7;
                hwb[(size_t)wsl * HWSLOT + hw_off] = (unsigned short)wv;
                if (quad < 2) hob[jj][s_w] = (quad & 1) ? h1 : h0;
                __syncthreads();
            }
        }

        // ---- flush hob -> out, coalesced float4 ----
        {
            const int nf4 = (tend - t0) * (RR / 4);
            const float4* src = (const float4*)&hob[0][0];
            float4* dst = (float4*)(outw + (size_t)t0 * RR);
#pragma unroll
            for (int it = 0; it < 3; ++it) {
                int idx = it * NTHR + tid;
                if (idx < nf4) dst[idx] = src[idx];
            }
        }
    }
}

extern "C" void kernel_launch(void* const* d_in, const int* in_sizes, int n_in,
                              void* d_out, int out_size, void* d_ws, size_t ws_size,
                              hipStream_t stream) {
    const float* x    = (const float*)d_in[0];   // (64, 2048, 1)
    const float* W_in = (const float*)d_in[1];   // (256, 1)
    const float* W_fb = (const float*)d_in[2];   // (5, 256, 256)
    const float* tapw = (const float*)d_in[3];   // (5,)
    const float* bias = (const float*)d_in[4];   // (256,)
    float* out = (float*)d_out;                  // (64, 2048, 256)
    unsigned short* bp = (unsigned short*)d_ws;  // 640 KB packed bf16 B-fragments

    pack_weights<<<160, 256, 0, stream>>>(W_fb, tapw, bp);
    reservoir_mfma<<<BB, NTHR, 0, stream>>>(x, W_in, bias, bp, out);
}